// Round 6
// baseline (683.769 us; speedup 1.0000x reference)
//
#include <hip/hip_runtime.h>
#include <math.h>

#define DEVI __device__ __forceinline__

DEVI float rlane(float v, int l) {
    return __builtin_bit_cast(float, __builtin_amdgcn_readlane(__builtin_bit_cast(int, v), l));
}
DEVI float sigf(float v) { return 1.0f / (1.0f + __expf(-v)); }
DEVI float tanh_f(float v) {
    v = fminf(fmaxf(v, -15.0f), 15.0f);
    float e = __expf(2.0f * v);
    return (e - 1.0f) / (e + 1.0f);
}

// ---------------------------------------------------------------------------
// Kernel A: fused (b,t)-independent tables.
//   Qg[d*40+e]  = {kk[d][e], kb[e][d], kb[d][e], bb[d][e]}
//   KBg[d*32+q] = {K[d][2q], K[d][2q+1], B[d][2q], B[d][2q+1]}
//   beta[t]     = (|bw_t|+1e-8)/sum
// ---------------------------------------------------------------------------
__global__ void precompute_kernel(const float* __restrict__ Kg, const float* __restrict__ Bg,
                                  const float* __restrict__ betaw,
                                  float4* __restrict__ Qg, float4* __restrict__ KBg,
                                  float* __restrict__ beta) {
    int job = blockIdx.x * 256 + threadIdx.x;
    if (job < 1600) {
        int d = job / 40, e = job - d * 40;
        const float* kd = Kg + d * 64;
        const float* ke = Kg + e * 64;
        const float* bd = Bg + d * 64;
        const float* be = Bg + e * 64;
        float kk = 0, kbT = 0, kbr = 0, bb = 0;
        for (int u = 0; u < 64; ++u) {
            kk  = fmaf(kd[u], ke[u], kk);
            kbT = fmaf(ke[u], bd[u], kbT);
            kbr = fmaf(kd[u], be[u], kbr);
            bb  = fmaf(bd[u], be[u], bb);
        }
        Qg[job] = make_float4(kk, kbT, kbr, bb);
    } else if (job < 2880) {
        int j2 = job - 1600;
        int d = j2 >> 5, q = j2 & 31;
        KBg[j2] = make_float4(Kg[d * 64 + 2 * q], Kg[d * 64 + 2 * q + 1],
                              Bg[d * 64 + 2 * q], Bg[d * 64 + 2 * q + 1]);
    }
    if (blockIdx.x == 0) {
        int tid = threadIdx.x;
        __shared__ float red[256];
        float av = (tid < 128) ? (fabsf(betaw[tid]) + 1e-8f) : 0.0f;
        red[tid] = av;
        __syncthreads();
        for (int s = 128; s > 0; s >>= 1) {
            if (tid < s) red[tid] += red[tid + s];
            __syncthreads();
        }
        float tot = red[0];
        if (tid < 128) beta[tid] = av / tot;
    }
}

// ---------------------------------------------------------------------------
// Kernel B1: input GEMM g[bt,j] = sum_d x[bt,d] W[d,j] + b[j]. No recurrence,
// fully parallel: 2048 blocks x 256, TILE=16 bt rows per block.
// ---------------------------------------------------------------------------
template <int K>
__global__ void xw_kernel(const float* __restrict__ x, const float* __restrict__ W,
                          const float* __restrict__ bvec, float* __restrict__ g) {
    __shared__ float xs[16 * K];
    int tid = threadIdx.x;
    int r0 = blockIdx.x * 16;
    const float4* xg = (const float4*)(x + (size_t)r0 * K);
    float4* xl = (float4*)xs;
    for (int i = tid; i < 16 * K / 4; i += 256) xl[i] = xg[i];
    float wcol[K];
#pragma unroll
    for (int d = 0; d < K; ++d) wcol[d] = W[d * 256 + tid];
    float bj = bvec[tid];
    __syncthreads();
    float* go = g + (size_t)r0 * 256 + tid;
#pragma unroll 1
    for (int r = 0; r < 16; ++r) {
        float a0 = bj, a1 = 0.f, a2 = 0.f, a3 = 0.f;
#pragma unroll
        for (int d = 0; d < K; d += 4) {
            a0 = fmaf(xs[r * K + d], wcol[d], a0);
            a1 = fmaf(xs[r * K + d + 1], wcol[d + 1], a1);
            a2 = fmaf(xs[r * K + d + 2], wcol[d + 2], a2);
            a3 = fmaf(xs[r * K + d + 3], wcol[d + 3], a3);
        }
        go[(size_t)r * 256] = (a0 + a1) + (a2 + a3);
    }
}

// ---------------------------------------------------------------------------
// Kernel B2: recurrence only: z = g[b,t] + h@U; h replicated in each wave's
// registers (lane=unit), one barrier per step, g prefetched.
// ---------------------------------------------------------------------------
__global__ void lstm_rec_kernel(const float* __restrict__ g, const float* __restrict__ U,
                                float* __restrict__ hout) {
    int b = blockIdx.x;
    int tid = threadIdx.x;
    int u = tid & 63;
    float ucol[64];
#pragma unroll
    for (int k = 0; k < 64; ++k) ucol[k] = U[k * 256 + tid];
    __shared__ float a_lds[2][256];
    float c = 0.0f, h = 0.0f;
    const float* gb = g + (size_t)b * 128 * 256;
    float gp = gb[tid];
#pragma unroll 1
    for (int t = 0; t < 128; ++t) {
        float gt = gp;
        if (t < 127) gp = gb[(t + 1) * 256 + tid];
        float a0 = gt, a1 = 0.f, a2 = 0.f, a3 = 0.f;
#pragma unroll
        for (int k = 0; k < 64; k += 4) {
            a0 = fmaf(rlane(h, k), ucol[k], a0);
            a1 = fmaf(rlane(h, k + 1), ucol[k + 1], a1);
            a2 = fmaf(rlane(h, k + 2), ucol[k + 2], a2);
            a3 = fmaf(rlane(h, k + 3), ucol[k + 3], a3);
        }
        float z = (a0 + a1) + (a2 + a3);
        int gate = tid >> 6;
        float a = (gate == 2) ? tanh_f(z) : sigf(z);
        int buf = t & 1;
        a_lds[buf][tid] = a;
        __syncthreads();
        float iv = a_lds[buf][u], fv = a_lds[buf][u + 64];
        float gv = a_lds[buf][u + 128], ov = a_lds[buf][u + 192];
        c = fmaf(fv, c, iv * gv);
        h = ov * tanh_f(c);
        if (tid < 64) hout[((size_t)b * 128 + t) * 64 + u] = h;
    }
}

// ---------------------------------------------------------------------------
// Fallback fused LSTM (R5) for small workspaces.
// ---------------------------------------------------------------------------
template <int DIN>
__launch_bounds__(512, 2)
__global__ void lstm_kernel(const float* __restrict__ xin, const float* __restrict__ W,
                            const float* __restrict__ U, const float* __restrict__ bvec,
                            float* __restrict__ hout) {
    constexpr int HD = DIN / 2;
    int b = blockIdx.x;
    int tid = threadIdx.x;
    int j = tid & 255;
    int half = tid >> 8;
    int lane = tid & 63;
    int hb = __builtin_amdgcn_readfirstlane(tid) >> 8;

    float wcol[HD];
    float ucol[32];
#pragma unroll
    for (int d = 0; d < HD; ++d) wcol[d] = W[(half * HD + d) * 256 + j];
#pragma unroll
    for (int k = 0; k < 32; ++k) ucol[k] = U[(half * 32 + k) * 256 + j];
    float bj = (tid < 256) ? bvec[j] : 0.0f;

    __shared__ float x_lds[128 * DIN];
    __shared__ float part[512];
    __shared__ float a_lds[256];
    __shared__ float h_lds[64];
    const float4* xg = (const float4*)(xin + (size_t)b * 128 * DIN);
    float4* xl = (float4*)x_lds;
    for (int i = tid; i < 128 * DIN / 4; i += 512) xl[i] = xg[i];
    if (tid < 64) h_lds[tid] = 0.0f;
    float c = 0.0f;
    __syncthreads();

    int li = (lane < DIN) ? lane : 0;
    for (int t = 0; t < 128; ++t) {
        float xv = x_lds[t * DIN + li];
        float hv = h_lds[lane];
        float a0 = 0.0f, a1 = 0.0f, a2 = 0.0f, a3 = 0.0f;
        if (hb == 0) {
#pragma unroll
            for (int d = 0; d < HD; d += 4) {
                a0 = fmaf(rlane(xv, d), wcol[d], a0);
                a1 = fmaf(rlane(xv, d + 1), wcol[d + 1], a1);
                a2 = fmaf(rlane(xv, d + 2), wcol[d + 2], a2);
                a3 = fmaf(rlane(xv, d + 3), wcol[d + 3], a3);
            }
#pragma unroll
            for (int k = 0; k < 32; k += 4) {
                a0 = fmaf(rlane(hv, k), ucol[k], a0);
                a1 = fmaf(rlane(hv, k + 1), ucol[k + 1], a1);
                a2 = fmaf(rlane(hv, k + 2), ucol[k + 2], a2);
                a3 = fmaf(rlane(hv, k + 3), ucol[k + 3], a3);
            }
        } else {
#pragma unroll
            for (int d = 0; d < HD; d += 4) {
                a0 = fmaf(rlane(xv, HD + d), wcol[d], a0);
                a1 = fmaf(rlane(xv, HD + d + 1), wcol[d + 1], a1);
                a2 = fmaf(rlane(xv, HD + d + 2), wcol[d + 2], a2);
                a3 = fmaf(rlane(xv, HD + d + 3), wcol[d + 3], a3);
            }
#pragma unroll
            for (int k = 0; k < 32; k += 4) {
                a0 = fmaf(rlane(hv, 32 + k), ucol[k], a0);
                a1 = fmaf(rlane(hv, 32 + k + 1), ucol[k + 1], a1);
                a2 = fmaf(rlane(hv, 32 + k + 2), ucol[k + 2], a2);
                a3 = fmaf(rlane(hv, 32 + k + 3), ucol[k + 3], a3);
            }
        }
        part[tid] = (a0 + a1) + (a2 + a3);
        __syncthreads();
        if (tid < 256) {
            float acc = part[tid] + part[tid + 256] + bj;
            int g = tid >> 6;
            float a = (g == 2) ? tanh_f(acc) : sigf(acc);
            a_lds[tid] = a;
        }
        __syncthreads();
        if (tid < 64) {
            float iv = a_lds[tid], fv = a_lds[tid + 64];
            float gv = a_lds[tid + 128], ov = a_lds[tid + 192];
            c = fmaf(fv, c, iv * gv);
            float h = ov * tanh_f(c);
            h_lds[tid] = h;
            hout[((size_t)b * 128 + t) * 64 + tid] = h;
        }
        __syncthreads();
    }
}

// ---------------------------------------------------------------------------
// Kernel C: attention. Templated NS-stream register-GE solve; a wave covers
// 16 t as 4 triples + 2 pairs (6 issue chains/SIMD in the triple phase).
// ---------------------------------------------------------------------------
template <int NS>
DEVI void solveN(const float* __restrict__ xr, const float* __restrict__ yr,
                 const float4* __restrict__ Qrow, const float4* __restrict__ KBrow,
                 int lane, float* __restrict__ alpha) {
    float t1a[NS], t1b[NS], t2a[NS], t2b[NS];
#pragma unroll
    for (int n = 0; n < NS; ++n) { t1a[n] = 0.f; t1b[n] = 0.f; t2a[n] = 0.f; t2b[n] = 0.f; }
#pragma unroll
    for (int q = 0; q < 32; ++q) {
        float4 kb = KBrow[q];
#pragma unroll
        for (int n = 0; n < NS; ++n) {
            float y0 = rlane(yr[n], 2 * q);
            float y1 = rlane(yr[n], 2 * q + 1);
            t1a[n] = fmaf(kb.x, y0, t1a[n]);
            t1b[n] = fmaf(kb.y, y1, t1b[n]);
            t2a[n] = fmaf(kb.z, y0, t2a[n]);
            t2b[n] = fmaf(kb.w, y1, t2b[n]);
        }
    }
    float A[41][NS];
#pragma unroll
    for (int n = 0; n < NS; ++n)
        A[40][n] = fmaf(xr[n], t1a[n] + t1b[n], t2a[n] + t2b[n]);
#pragma unroll
    for (int e = 0; e < 40; ++e) {
        float4 q4 = Qrow[e];
#pragma unroll
        for (int n = 0; n < NS; ++n) {
            float sxe = rlane(xr[n], e);
            A[e][n] = fmaf(sxe, fmaf(xr[n], q4.x, q4.y), fmaf(xr[n], q4.z, q4.w));
        }
    }
    // GE forward elimination (PD Gram, no pivoting), rcp pivots
    float rpl[NS];
#pragma unroll
    for (int n = 0; n < NS; ++n) rpl[n] = 0.f;
#pragma unroll
    for (int k = 0; k < 40; ++k) {
        bool eq = (lane == k), gt = (lane > k);
        float m[NS];
#pragma unroll
        for (int n = 0; n < NS; ++n) {
            float rp = __builtin_amdgcn_rcpf(rlane(A[k][n], k));
            rpl[n] = eq ? rp : rpl[n];
            m[n] = gt ? A[k][n] * rp : 0.f;
        }
#pragma unroll
        for (int jj = k + 1; jj <= 40; ++jj) {
#pragma unroll
            for (int n = 0; n < NS; ++n)
                A[jj][n] = fmaf(-m[n], rlane(A[jj][n], k), A[jj][n]);
        }
    }
    // Back substitution (division-free)
    float acc[NS];
#pragma unroll
    for (int n = 0; n < NS; ++n) { acc[n] = A[40][n]; alpha[n] = 0.f; }
#pragma unroll
    for (int k = 39; k >= 0; --k) {
        bool eq = (lane == k);
#pragma unroll
        for (int n = 0; n < NS; ++n) {
            float xk = rlane(acc[n], k) * rlane(rpl[n], k);
            alpha[n] = eq ? xk : alpha[n];
            acc[n] = fmaf(-xk, A[k][n], acc[n]);
        }
    }
}

__launch_bounds__(256)
__global__ void attn_kernel(const float* __restrict__ xin, const float* __restrict__ yin,
                            const float4* __restrict__ Qg, const float4* __restrict__ KBg,
                            const float* __restrict__ betap, float* __restrict__ zpart) {
    __shared__ float4 sQ4[40 * 41];
    __shared__ float4 sKB4[40 * 33];
    __shared__ float redW[4][64];
    __shared__ float redA[4][64];
    __shared__ float wsf[64];
    __shared__ float asf[64];
    int tid = threadIdx.x;
    for (int i = tid; i < 1600; i += 256) {
        int d = i / 40, e = i - d * 40;
        sQ4[d * 41 + e] = Qg[i];
    }
    for (int i = tid; i < 1280; i += 256) {
        int d = i >> 5, q = i & 31;
        sKB4[d * 33 + q] = KBg[i];
    }
    __syncthreads();

    int b = blockIdx.x >> 1;
    int half = blockIdx.x & 1;
    int wv = tid >> 6;
    int lane = tid & 63;
    int rl0 = (lane < 40) ? lane : 39;
    const float4* Qrow = sQ4 + rl0 * 41;
    const float4* KBrow = sKB4 + rl0 * 33;

    float wsacc = 0.f, asacc = 0.f;
    int t0 = half * 64 + wv * 16;
    size_t bt0 = (size_t)b * 128 + t0;

    // 4 triples
#pragma unroll 1
    for (int grp = 0; grp < 4; ++grp) {
        int tg = grp * 3;
        float xr[3], yr[3], alpha[3];
#pragma unroll
        for (int n = 0; n < 3; ++n) {
            xr[n] = xin[(bt0 + tg + n) * 40 + rl0];
            yr[n] = yin[(bt0 + tg + n) * 64 + lane];
            if (lane >= 40) xr[n] = 0.f;
        }
        solveN<3>(xr, yr, Qrow, KBrow, lane, alpha);
#pragma unroll
        for (int n = 0; n < 3; ++n) {
            float bt = betap[t0 + tg + n];
            wsacc = fmaf(bt, alpha[n] * xr[n], wsacc);
            asacc = fmaf(bt, alpha[n], asacc);
        }
    }
    // 2 pairs
#pragma unroll 1
    for (int grp = 0; grp < 2; ++grp) {
        int tg = 12 + grp * 2;
        float xr[2], yr[2], alpha[2];
#pragma unroll
        for (int n = 0; n < 2; ++n) {
            xr[n] = xin[(bt0 + tg + n) * 40 + rl0];
            yr[n] = yin[(bt0 + tg + n) * 64 + lane];
            if (lane >= 40) xr[n] = 0.f;
        }
        solveN<2>(xr, yr, Qrow, KBrow, lane, alpha);
#pragma unroll
        for (int n = 0; n < 2; ++n) {
            float bt = betap[t0 + tg + n];
            wsacc = fmaf(bt, alpha[n] * xr[n], wsacc);
            asacc = fmaf(bt, alpha[n], asacc);
        }
    }

    redW[wv][lane] = wsacc;
    redA[wv][lane] = asacc;
    __syncthreads();
    if (tid < 64) {
        wsf[tid] = (redW[0][tid] + redW[1][tid]) + (redW[2][tid] + redW[3][tid]);
    } else if (tid < 128) {
        int d = tid - 64;
        asf[d] = (redA[0][d] + redA[1][d]) + (redA[2][d] + redA[3][d]);
    }
    __syncthreads();
    if (tid < 64) {
        const float* KBf = (const float*)sKB4;
        int u = tid;
        int off = ((u >> 1) << 2) + (u & 1);
        float z = 0.0f;
#pragma unroll
        for (int d = 0; d < 40; ++d) {
            float kv = KBf[d * 132 + off];
            float bv = KBf[d * 132 + off + 2];
            z = fmaf(wsf[d], kv, z);
            z = fmaf(asf[d], bv, z);
        }
        zpart[((size_t)b * 2 + half) * 64 + u] = z;
    }
}

// ---------------------------------------------------------------------------
// Kernel D: deterministic final reduce over the 2 half-blocks per b.
// ---------------------------------------------------------------------------
__global__ void reduce_kernel(const float* __restrict__ zpart, float* __restrict__ out) {
    int idx = blockIdx.x * 256 + threadIdx.x;
    int b = idx >> 6, u = idx & 63;
    const float* zp = zpart + (size_t)b * 2 * 64 + u;
    out[idx] = zp[0] + zp[64];
}

// ---------------------------------------------------------------------------
extern "C" void kernel_launch(void* const* d_in, const int* in_sizes, int n_in,
                              void* d_out, int out_size, void* d_ws, size_t ws_size,
                              hipStream_t stream) {
    const float* x  = (const float*)d_in[0];
    const float* W0 = (const float*)d_in[1];
    const float* U0 = (const float*)d_in[2];
    const float* b0 = (const float*)d_in[3];
    const float* W1 = (const float*)d_in[4];
    const float* U1 = (const float*)d_in[5];
    const float* b1 = (const float*)d_in[6];
    const float* Kg = (const float*)d_in[7];
    const float* Bg = (const float*)d_in[8];
    const float* bw = (const float*)d_in[9];
    float* out = (float*)d_out;

    if (ws_size >= (size_t)51 * 1024 * 1024) {
        // Big path: precomputed input GEMM + recurrence-only LSTM kernels.
        float* g    = (float*)d_ws;                    // 8,388,608 f32
        float* h0   = g + (size_t)32768 * 256;         // 2,097,152 f32
        float* y    = h0 + (size_t)32768 * 64;         // 2,097,152 f32
        float4* Qg  = (float4*)(y + (size_t)32768 * 64);
        float4* KBg = Qg + 1600;
        float* beta = (float*)(KBg + 1280);
        float* zpart = beta + 128;

        precompute_kernel<<<12, 256, 0, stream>>>(Kg, Bg, bw, Qg, KBg, beta);
        xw_kernel<40><<<2048, 256, 0, stream>>>(x, W0, b0, g);
        lstm_rec_kernel<<<256, 256, 0, stream>>>(g, U0, h0);
        xw_kernel<64><<<2048, 256, 0, stream>>>(h0, W1, b1, g);
        lstm_rec_kernel<<<256, 256, 0, stream>>>(g, U1, y);
        attn_kernel<<<512, 256, 0, stream>>>(x, y, Qg, KBg, beta, zpart);
        reduce_kernel<<<64, 256, 0, stream>>>(zpart, out);
    } else {
        // Fallback: fused LSTM (R5 path).
        float* h0    = (float*)d_ws;
        float* y     = h0 + 256 * 128 * 64;
        float4* Qg   = (float4*)(y + 256 * 128 * 64);
        float4* KBg  = Qg + 1600;
        float* beta  = (float*)(KBg + 1280);
        float* zpart = h0;  // overlays h0 (dead by attn time)

        precompute_kernel<<<12, 256, 0, stream>>>(Kg, Bg, bw, Qg, KBg, beta);
        lstm_kernel<40><<<256, 512, 0, stream>>>(x, W0, U0, b0, h0);
        lstm_kernel<64><<<256, 512, 0, stream>>>(h0, W1, U1, b1, y);
        attn_kernel<<<512, 256, 0, stream>>>(x, y, Qg, KBg, beta, zpart);
        reduce_kernel<<<64, 256, 0, stream>>>(zpart, out);
    }
}

// Round 7
// 533.258 us; speedup vs baseline: 1.2822x; 1.2822x over previous
//
#include <hip/hip_runtime.h>
#include <math.h>

#define DEVI __device__ __forceinline__

DEVI float rlane(float v, int l) {
    return __builtin_bit_cast(float, __builtin_amdgcn_readlane(__builtin_bit_cast(int, v), l));
}
DEVI float sigf(float v) { return 1.0f / (1.0f + __expf(-v)); }
DEVI float tanh_f(float v) {
    v = fminf(fmaxf(v, -15.0f), 15.0f);
    float e = __expf(2.0f * v);
    return (e - 1.0f) / (e + 1.0f);
}

// ---------------------------------------------------------------------------
// Kernel A: fused (b,t)-independent tables.
//   Qg[d*40+e]  = {kk[d][e], kb[e][d], kb[d][e], bb[d][e]}
//   KBg[d*32+q] = {K[d][2q], K[d][2q+1], B[d][2q], B[d][2q+1]}
//   beta[t]     = (|bw_t|+1e-8)/sum
// ---------------------------------------------------------------------------
__global__ void precompute_kernel(const float* __restrict__ Kg, const float* __restrict__ Bg,
                                  const float* __restrict__ betaw,
                                  float4* __restrict__ Qg, float4* __restrict__ KBg,
                                  float* __restrict__ beta) {
    int job = blockIdx.x * 256 + threadIdx.x;
    if (job < 1600) {
        int d = job / 40, e = job - d * 40;
        const float* kd = Kg + d * 64;
        const float* ke = Kg + e * 64;
        const float* bd = Bg + d * 64;
        const float* be = Bg + e * 64;
        float kk = 0, kbT = 0, kbr = 0, bb = 0;
        for (int u = 0; u < 64; ++u) {
            kk  = fmaf(kd[u], ke[u], kk);
            kbT = fmaf(ke[u], bd[u], kbT);
            kbr = fmaf(kd[u], be[u], kbr);
            bb  = fmaf(bd[u], be[u], bb);
        }
        Qg[job] = make_float4(kk, kbT, kbr, bb);
    } else if (job < 2880) {
        int j2 = job - 1600;
        int d = j2 >> 5, q = j2 & 31;
        KBg[j2] = make_float4(Kg[d * 64 + 2 * q], Kg[d * 64 + 2 * q + 1],
                              Bg[d * 64 + 2 * q], Bg[d * 64 + 2 * q + 1]);
    }
    if (blockIdx.x == 0) {
        int tid = threadIdx.x;
        __shared__ float red[256];
        float av = (tid < 128) ? (fabsf(betaw[tid]) + 1e-8f) : 0.0f;
        red[tid] = av;
        __syncthreads();
        for (int s = 128; s > 0; s >>= 1) {
            if (tid < s) red[tid] += red[tid + s];
            __syncthreads();
        }
        float tot = red[0];
        if (tid < 128) beta[tid] = av / tot;
    }
}

// ---------------------------------------------------------------------------
// Kernel B: fused LSTM layer (gates i,f,g,o), one 512-thread block per batch
// row. K-split halves; ONE barrier per step: after the part[] reduction every
// thread redundantly computes all 4 gates for its u=tid&63 and updates a
// replicated (c,h) — bit-identical across threads, so deterministic. part[]
// is double-buffered to remove the second barrier.
// ---------------------------------------------------------------------------
template <int DIN>
__launch_bounds__(512)
__global__ void lstm_kernel(const float* __restrict__ xin, const float* __restrict__ W,
                            const float* __restrict__ U, const float* __restrict__ bvec,
                            float* __restrict__ hout) {
    constexpr int HD = DIN / 2;
    int b = blockIdx.x;
    int tid = threadIdx.x;
    int j = tid & 255;           // gate column 0..255
    int half = tid >> 8;         // K-split half
    int u = tid & 63;            // unit id
    int hb = __builtin_amdgcn_readfirstlane(tid) >> 8;  // wave-uniform half id

    float wcol[HD];
    float ucol[32];
#pragma unroll
    for (int d = 0; d < HD; ++d) wcol[d] = W[(half * HD + d) * 256 + j];
#pragma unroll
    for (int k = 0; k < 32; ++k) ucol[k] = U[(half * 32 + k) * 256 + j];
    float bi = bvec[u], bf = bvec[u + 64], bg = bvec[u + 128], bo = bvec[u + 192];

    __shared__ float x_lds[128 * DIN];
    __shared__ float part[2][512];
    const float4* xg = (const float4*)(xin + (size_t)b * 128 * DIN);
    float4* xl = (float4*)x_lds;
    for (int i = tid; i < 128 * DIN / 4; i += 512) xl[i] = xg[i];
    float c = 0.0f, h = 0.0f;
    __syncthreads();

    int li = (u < DIN) ? u : 0;
    for (int t = 0; t < 128; ++t) {
        float xv = x_lds[t * DIN + li];   // lane l holds x[t][l] (l<DIN)
        float a0 = 0.0f, a1 = 0.0f, a2 = 0.0f, a3 = 0.0f;
        if (hb == 0) {
#pragma unroll
            for (int d = 0; d < HD; d += 4) {
                a0 = fmaf(rlane(xv, d), wcol[d], a0);
                a1 = fmaf(rlane(xv, d + 1), wcol[d + 1], a1);
                a2 = fmaf(rlane(xv, d + 2), wcol[d + 2], a2);
                a3 = fmaf(rlane(xv, d + 3), wcol[d + 3], a3);
            }
#pragma unroll
            for (int k = 0; k < 32; k += 4) {
                a0 = fmaf(rlane(h, k), ucol[k], a0);
                a1 = fmaf(rlane(h, k + 1), ucol[k + 1], a1);
                a2 = fmaf(rlane(h, k + 2), ucol[k + 2], a2);
                a3 = fmaf(rlane(h, k + 3), ucol[k + 3], a3);
            }
        } else {
#pragma unroll
            for (int d = 0; d < HD; d += 4) {
                a0 = fmaf(rlane(xv, HD + d), wcol[d], a0);
                a1 = fmaf(rlane(xv, HD + d + 1), wcol[d + 1], a1);
                a2 = fmaf(rlane(xv, HD + d + 2), wcol[d + 2], a2);
                a3 = fmaf(rlane(xv, HD + d + 3), wcol[d + 3], a3);
            }
#pragma unroll
            for (int k = 0; k < 32; k += 4) {
                a0 = fmaf(rlane(h, 32 + k), ucol[k], a0);
                a1 = fmaf(rlane(h, 32 + k + 1), ucol[k + 1], a1);
                a2 = fmaf(rlane(h, 32 + k + 2), ucol[k + 2], a2);
                a3 = fmaf(rlane(h, 32 + k + 3), ucol[k + 3], a3);
            }
        }
        int buf = t & 1;
        part[buf][tid] = (a0 + a1) + (a2 + a3);
        __syncthreads();
        const float* pp = part[buf];
        float zi = pp[u] + pp[u + 256] + bi;
        float zf = pp[u + 64] + pp[u + 320] + bf;
        float zg = pp[u + 128] + pp[u + 384] + bg;
        float zo = pp[u + 192] + pp[u + 448] + bo;
        float iv = sigf(zi), fv = sigf(zf), gv = tanh_f(zg), ov = sigf(zo);
        c = fmaf(fv, c, iv * gv);
        h = ov * tanh_f(c);
        if (tid < 64) hout[((size_t)b * 128 + t) * 64 + u] = h;
    }
}

// ---------------------------------------------------------------------------
// Kernel C: attention (R5-proven NS=2). 2 solves per wave (float2 streams),
// spill-free; amdgpu_waves_per_eu(3) asks for a true 170-VGPR cap for
// 3 waves/SIMD (launch_bounds' 2nd arg halves the budget — avoid it).
// Grid 512 x 256 (half-b per block, 16 t per wave).
// ---------------------------------------------------------------------------
DEVI float2 rlane2(float2 v, int l) {
    return make_float2(rlane(v.x, l), rlane(v.y, l));
}

__launch_bounds__(256)
__attribute__((amdgpu_waves_per_eu(3)))
__global__ void attn_kernel(const float* __restrict__ xin, const float* __restrict__ yin,
                            const float4* __restrict__ Qg, const float4* __restrict__ KBg,
                            const float* __restrict__ betap, float* __restrict__ zpart) {
    __shared__ float4 sQ4[40 * 41];   // 26.2 KB
    __shared__ float4 sKB4[40 * 33];  // 21.1 KB
    __shared__ float redW[4][64];
    __shared__ float redA[4][64];
    __shared__ float wsf[64];
    __shared__ float asf[64];
    int tid = threadIdx.x;
    for (int i = tid; i < 1600; i += 256) {
        int d = i / 40, e = i - d * 40;
        sQ4[d * 41 + e] = Qg[i];
    }
    for (int i = tid; i < 1280; i += 256) {
        int d = i >> 5, q = i & 31;
        sKB4[d * 33 + q] = KBg[i];
    }
    __syncthreads();

    int b = blockIdx.x >> 1;
    int half = blockIdx.x & 1;
    int wv = tid >> 6;
    int lane = tid & 63;
    int rl0 = (lane < 40) ? lane : 39;
    const float4* Qrow = sQ4 + rl0 * 41;
    const float4* KBrow = sKB4 + rl0 * 33;

    float2 wsacc = make_float2(0.f, 0.f);
    float2 asacc = make_float2(0.f, 0.f);
    int t0 = half * 64 + wv * 16;
    size_t bt0 = (size_t)b * 128 + t0;

    float2 xp, yp;
    xp.x = xin[(bt0 + 0) * 40 + rl0];
    xp.y = xin[(bt0 + 1) * 40 + rl0];
    yp.x = yin[(bt0 + 0) * 64 + lane];
    yp.y = yin[(bt0 + 1) * 64 + lane];

#pragma unroll 1
    for (int it = 0; it < 8; ++it) {
        float2 xv = xp, yv = yp;
        float2 bt2 = make_float2(betap[t0 + 2 * it], betap[t0 + 2 * it + 1]);
        if (it < 7) {
            size_t gn = bt0 + 2 * it + 2;
            xp.x = xin[(gn + 0) * 40 + rl0];
            xp.y = xin[(gn + 1) * 40 + rl0];
            yp.x = yin[(gn + 0) * 64 + lane];
            yp.y = yin[(gn + 1) * 64 + lane];
        }
        if (lane >= 40) xv = make_float2(0.f, 0.f);

        // t1 = (K y)_d, t2 = (B y)_d per stream; table quads shared
        float2 t1a = make_float2(0.f, 0.f), t1b = t1a, t2a = t1a, t2b = t1a;
#pragma unroll
        for (int q = 0; q < 32; ++q) {
            float4 kb = KBrow[q];
            float2 y0 = rlane2(yv, 2 * q);
            float2 y1 = rlane2(yv, 2 * q + 1);
            t1a.x = fmaf(kb.x, y0.x, t1a.x); t1a.y = fmaf(kb.x, y0.y, t1a.y);
            t1b.x = fmaf(kb.y, y1.x, t1b.x); t1b.y = fmaf(kb.y, y1.y, t1b.y);
            t2a.x = fmaf(kb.z, y0.x, t2a.x); t2a.y = fmaf(kb.z, y0.y, t2a.y);
            t2b.x = fmaf(kb.w, y1.x, t2b.x); t2b.y = fmaf(kb.w, y1.y, t2b.y);
        }

        float2 A[41];
        A[40].x = fmaf(xv.x, t1a.x + t1b.x, t2a.x + t2b.x);
        A[40].y = fmaf(xv.y, t1a.y + t1b.y, t2a.y + t2b.y);
#pragma unroll
        for (int e = 0; e < 40; ++e) {
            float4 q4 = Qrow[e];
            float2 sxe = rlane2(xv, e);
            A[e].x = fmaf(sxe.x, fmaf(xv.x, q4.x, q4.y), fmaf(xv.x, q4.z, q4.w));
            A[e].y = fmaf(sxe.y, fmaf(xv.y, q4.x, q4.y), fmaf(xv.y, q4.z, q4.w));
        }

        // GE forward elimination (PD Gram, no pivoting), 2 streams interleaved
        float2 rpl = make_float2(0.f, 0.f);
#pragma unroll
        for (int k = 0; k < 40; ++k) {
            float2 piv = rlane2(A[k], k);
            float2 rp;
            rp.x = __builtin_amdgcn_rcpf(piv.x);
            rp.y = __builtin_amdgcn_rcpf(piv.y);
            bool eq = (lane == k);
            rpl.x = eq ? rp.x : rpl.x;
            rpl.y = eq ? rp.y : rpl.y;
            bool gt = (lane > k);
            float2 m;
            m.x = gt ? A[k].x * rp.x : 0.f;
            m.y = gt ? A[k].y * rp.y : 0.f;
#pragma unroll
            for (int jj = k + 1; jj <= 40; ++jj) {
                float2 r = rlane2(A[jj], k);
                A[jj].x = fmaf(-m.x, r.x, A[jj].x);
                A[jj].y = fmaf(-m.y, r.y, A[jj].y);
            }
        }

        // Back substitution (division-free)
        float2 acc = A[40];
        float2 alpha = make_float2(0.f, 0.f);
#pragma unroll
        for (int k = 39; k >= 0; --k) {
            float2 na = rlane2(acc, k);
            float2 rk = rlane2(rpl, k);
            float2 xk = make_float2(na.x * rk.x, na.y * rk.y);
            bool eq = (lane == k);
            alpha.x = eq ? xk.x : alpha.x;
            alpha.y = eq ? xk.y : alpha.y;
            acc.x = fmaf(-xk.x, A[k].x, acc.x);
            acc.y = fmaf(-xk.y, A[k].y, acc.y);
        }

        wsacc.x = fmaf(bt2.x, alpha.x * xv.x, wsacc.x);
        wsacc.y = fmaf(bt2.y, alpha.y * xv.y, wsacc.y);
        asacc.x = fmaf(bt2.x, alpha.x, asacc.x);
        asacc.y = fmaf(bt2.y, alpha.y, asacc.y);
    }

    redW[wv][lane] = wsacc.x + wsacc.y;
    redA[wv][lane] = asacc.x + asacc.y;
    __syncthreads();
    if (tid < 64) {
        wsf[tid] = (redW[0][tid] + redW[1][tid]) + (redW[2][tid] + redW[3][tid]);
    } else if (tid < 128) {
        int d = tid - 64;
        asf[d] = (redA[0][d] + redA[1][d]) + (redA[2][d] + redA[3][d]);
    }
    __syncthreads();
    if (tid < 64) {
        const float* KBf = (const float*)sKB4;
        int u = tid;
        int off = ((u >> 1) << 2) + (u & 1);
        float z = 0.0f;
#pragma unroll
        for (int d = 0; d < 40; ++d) {
            float kv = KBf[d * 132 + off];
            float bv = KBf[d * 132 + off + 2];
            z = fmaf(wsf[d], kv, z);
            z = fmaf(asf[d], bv, z);
        }
        zpart[((size_t)b * 2 + half) * 64 + u] = z;
    }
}

// ---------------------------------------------------------------------------
// Kernel D: deterministic final reduce over the 2 half-blocks per b.
// ---------------------------------------------------------------------------
__global__ void reduce_kernel(const float* __restrict__ zpart, float* __restrict__ out) {
    int idx = blockIdx.x * 256 + threadIdx.x;  // 16384 = 256*64
    int b = idx >> 6, u = idx & 63;
    const float* zp = zpart + (size_t)b * 2 * 64 + u;
    out[idx] = zp[0] + zp[64];
}

// ---------------------------------------------------------------------------
extern "C" void kernel_launch(void* const* d_in, const int* in_sizes, int n_in,
                              void* d_out, int out_size, void* d_ws, size_t ws_size,
                              hipStream_t stream) {
    const float* x  = (const float*)d_in[0];
    const float* W0 = (const float*)d_in[1];
    const float* U0 = (const float*)d_in[2];
    const float* b0 = (const float*)d_in[3];
    const float* W1 = (const float*)d_in[4];
    const float* U1 = (const float*)d_in[5];
    const float* b1 = (const float*)d_in[6];
    const float* Kg = (const float*)d_in[7];
    const float* Bg = (const float*)d_in[8];
    const float* bw = (const float*)d_in[9];
    float* out = (float*)d_out;

    float* h0    = (float*)d_ws;                   // 2,097,152 f32
    float* y     = h0 + 256 * 128 * 64;            // 2,097,152 f32
    float4* Qg   = (float4*)(y + 256 * 128 * 64);  // 1600 float4
    float4* KBg  = Qg + 1600;                      // 1280 float4
    float* beta  = (float*)(KBg + 1280);           // 128 f32
    float* zpart = h0;                             // 32,768 f32, overlays h0 (dead)

    precompute_kernel<<<12, 256, 0, stream>>>(Kg, Bg, bw, Qg, KBg, beta);
    lstm_kernel<40><<<256, 512, 0, stream>>>(x, W0, U0, b0, h0);
    lstm_kernel<64><<<256, 512, 0, stream>>>(h0, W1, U1, b1, y);
    attn_kernel<<<512, 256, 0, stream>>>(x, y, Qg, KBg, beta, zpart);
    reduce_kernel<<<64, 256, 0, stream>>>(zpart, out);
}

// Round 8
// 396.593 us; speedup vs baseline: 1.7241x; 1.3446x over previous
//
#include <hip/hip_runtime.h>
#include <math.h>

#define DEVI __device__ __forceinline__

DEVI float rlane(float v, int l) {
    return __builtin_bit_cast(float, __builtin_amdgcn_readlane(__builtin_bit_cast(int, v), l));
}
DEVI float2 rlane2(float2 v, int l) {
    return make_float2(rlane(v.x, l), rlane(v.y, l));
}
DEVI float sigf(float v) { return 1.0f / (1.0f + __expf(-v)); }
DEVI float tanh_f(float v) {
    v = fminf(fmaxf(v, -15.0f), 15.0f);
    float e = __expf(2.0f * v);
    return (e - 1.0f) / (e + 1.0f);
}

// ---------------------------------------------------------------------------
// Kernel A: fused (b,t)-independent tables.
//   Qg[d*40+e]  = {kk[d][e], kb[e][d], kb[d][e], bb[d][e]}
//   KBg[d*32+q] = {K[d][2q], K[d][2q+1], B[d][2q], B[d][2q+1]}
//   beta[t]     = (|bw_t|+1e-8)/sum
// ---------------------------------------------------------------------------
__global__ void precompute_kernel(const float* __restrict__ Kg, const float* __restrict__ Bg,
                                  const float* __restrict__ betaw,
                                  float4* __restrict__ Qg, float4* __restrict__ KBg,
                                  float* __restrict__ beta) {
    int job = blockIdx.x * 256 + threadIdx.x;
    if (job < 1600) {
        int d = job / 40, e = job - d * 40;
        const float* kd = Kg + d * 64;
        const float* ke = Kg + e * 64;
        const float* bd = Bg + d * 64;
        const float* be = Bg + e * 64;
        float kk = 0, kbT = 0, kbr = 0, bb = 0;
        for (int u = 0; u < 64; ++u) {
            kk  = fmaf(kd[u], ke[u], kk);
            kbT = fmaf(ke[u], bd[u], kbT);
            kbr = fmaf(kd[u], be[u], kbr);
            bb  = fmaf(bd[u], be[u], bb);
        }
        Qg[job] = make_float4(kk, kbT, kbr, bb);
    } else if (job < 2880) {
        int j2 = job - 1600;
        int d = j2 >> 5, q = j2 & 31;
        KBg[j2] = make_float4(Kg[d * 64 + 2 * q], Kg[d * 64 + 2 * q + 1],
                              Bg[d * 64 + 2 * q], Bg[d * 64 + 2 * q + 1]);
    }
    if (blockIdx.x == 0) {
        int tid = threadIdx.x;
        __shared__ float red[256];
        float av = (tid < 128) ? (fabsf(betaw[tid]) + 1e-8f) : 0.0f;
        red[tid] = av;
        __syncthreads();
        for (int s = 128; s > 0; s >>= 1) {
            if (tid < s) red[tid] += red[tid + s];
            __syncthreads();
        }
        float tot = red[0];
        if (tid < 128) beta[tid] = av / tot;
    }
}

// ---------------------------------------------------------------------------
// Kernel B: BOTH LSTM layers in one kernel, software-pipelined over t.
// Group A (tid<256, waves 0-3) = layer 1 step s; group B (waves 4-7) =
// layer 2 step s-1 (consumes h1[s-1] from LDS). 129 steps, 2 barriers each.
// Each thread owns one gate-column: full dot in registers, self-activation
// (no cross-thread reduce); units 0-63 of each group update replicated-free
// (c,h) state and publish h to its LDS buffer.
// ---------------------------------------------------------------------------
__global__ __launch_bounds__(512)
void lstm2_kernel(const float* __restrict__ x,
                  const float* __restrict__ W0, const float* __restrict__ U0,
                  const float* __restrict__ b0,
                  const float* __restrict__ W1, const float* __restrict__ U1,
                  const float* __restrict__ b1,
                  float* __restrict__ y) {
    int b = blockIdx.x;
    int tid = threadIdx.x;
    int j = tid & 255;   // gate column
    int u = tid & 63;    // unit id
    int lane = tid & 63;
    int grp = __builtin_amdgcn_readfirstlane(tid) >> 8;  // wave-uniform layer id

    float wcol[64];
    float ucol[64];
    float bj;
    if (grp == 0) {
#pragma unroll
        for (int d = 0; d < 40; ++d) wcol[d] = W0[d * 256 + j];
#pragma unroll
        for (int k = 0; k < 64; ++k) ucol[k] = U0[k * 256 + j];
        bj = b0[j];
    } else {
#pragma unroll
        for (int k = 0; k < 64; ++k) wcol[k] = W1[k * 256 + j];
#pragma unroll
        for (int k = 0; k < 64; ++k) ucol[k] = U1[k * 256 + j];
        bj = b1[j];
    }

    __shared__ float x_lds[128 * 40];   // 20 KB
    __shared__ float a_lds[512];
    __shared__ float h1buf[64];
    __shared__ float h2buf[64];
    const float4* xg = (const float4*)(x + (size_t)b * 128 * 40);
    float4* xl = (float4*)x_lds;
    for (int i = tid; i < 128 * 40 / 4; i += 512) xl[i] = xg[i];
    if (tid < 64) { h1buf[tid] = 0.0f; h2buf[tid] = 0.0f; }
    float c1 = 0.0f, c2 = 0.0f;
    __syncthreads();

    int li = (lane < 40) ? lane : 0;
#pragma unroll 1
    for (int s = 0; s <= 128; ++s) {
        float a0 = bj, a1 = 0.0f, a2 = 0.0f, a3 = 0.0f;
        if (grp == 0) {
            if (s < 128) {
                float xv = x_lds[s * 40 + li];   // lane l holds x[s][l]
                float hv = h1buf[lane];          // h1[s-1]
#pragma unroll
                for (int d = 0; d < 40; d += 4) {
                    a0 = fmaf(rlane(xv, d), wcol[d], a0);
                    a1 = fmaf(rlane(xv, d + 1), wcol[d + 1], a1);
                    a2 = fmaf(rlane(xv, d + 2), wcol[d + 2], a2);
                    a3 = fmaf(rlane(xv, d + 3), wcol[d + 3], a3);
                }
#pragma unroll
                for (int k = 0; k < 64; k += 4) {
                    a0 = fmaf(rlane(hv, k), ucol[k], a0);
                    a1 = fmaf(rlane(hv, k + 1), ucol[k + 1], a1);
                    a2 = fmaf(rlane(hv, k + 2), ucol[k + 2], a2);
                    a3 = fmaf(rlane(hv, k + 3), ucol[k + 3], a3);
                }
            }
        } else {
            if (s >= 1) {
                float h1x = h1buf[lane];         // x2 = h1[s-1]
                float h2v = h2buf[lane];         // h2[s-2]
#pragma unroll
                for (int k = 0; k < 64; k += 4) {
                    a0 = fmaf(rlane(h1x, k), wcol[k], a0);
                    a1 = fmaf(rlane(h1x, k + 1), wcol[k + 1], a1);
                    a2 = fmaf(rlane(h1x, k + 2), wcol[k + 2], a2);
                    a3 = fmaf(rlane(h1x, k + 3), wcol[k + 3], a3);
                }
#pragma unroll
                for (int k = 0; k < 64; k += 4) {
                    a0 = fmaf(rlane(h2v, k), ucol[k], a0);
                    a1 = fmaf(rlane(h2v, k + 1), ucol[k + 1], a1);
                    a2 = fmaf(rlane(h2v, k + 2), ucol[k + 2], a2);
                    a3 = fmaf(rlane(h2v, k + 3), ucol[k + 3], a3);
                }
            }
        }
        float z = (a0 + a1) + (a2 + a3);
        int g = (tid >> 6) & 3;
        float a = (g == 2) ? tanh_f(z) : sigf(z);
        a_lds[tid] = a;
        __syncthreads();
        if (grp == 0) {
            if (tid < 64 && s < 128) {
                float iv = a_lds[u], fv = a_lds[u + 64];
                float gv = a_lds[u + 128], ov = a_lds[u + 192];
                c1 = fmaf(fv, c1, iv * gv);
                h1buf[u] = ov * tanh_f(c1);
            }
        } else {
            if (tid < 320 && s >= 1) {
                float iv = a_lds[256 + u], fv = a_lds[320 + u];
                float gv = a_lds[384 + u], ov = a_lds[448 + u];
                c2 = fmaf(fv, c2, iv * gv);
                float h2 = ov * tanh_f(c2);
                h2buf[u] = h2;
                y[((size_t)b * 128 + (s - 1)) * 64 + u] = h2;
            }
        }
        __syncthreads();
    }
}

// ---------------------------------------------------------------------------
// Kernel C: attention (R5-proven, UNCAPPED — any occupancy attribute makes
// the allocator spill A[] to scratch; verified R2/R3/R7). 2 solves per wave
// (float2 streams), table LDS reads shared. Grid 512 x 256.
// ---------------------------------------------------------------------------
__launch_bounds__(256)
__global__ void attn_kernel(const float* __restrict__ xin, const float* __restrict__ yin,
                            const float4* __restrict__ Qg, const float4* __restrict__ KBg,
                            const float* __restrict__ betap, float* __restrict__ zpart) {
    __shared__ float4 sQ4[40 * 41];   // 26.2 KB
    __shared__ float4 sKB4[40 * 33];  // 21.1 KB
    __shared__ float redW[4][64];
    __shared__ float redA[4][64];
    __shared__ float wsf[64];
    __shared__ float asf[64];
    int tid = threadIdx.x;
    for (int i = tid; i < 1600; i += 256) {
        int d = i / 40, e = i - d * 40;
        sQ4[d * 41 + e] = Qg[i];
    }
    for (int i = tid; i < 1280; i += 256) {
        int d = i >> 5, q = i & 31;
        sKB4[d * 33 + q] = KBg[i];
    }
    __syncthreads();

    int b = blockIdx.x >> 1;
    int half = blockIdx.x & 1;
    int wv = tid >> 6;
    int lane = tid & 63;
    int rl0 = (lane < 40) ? lane : 39;
    const float4* Qrow = sQ4 + rl0 * 41;
    const float4* KBrow = sKB4 + rl0 * 33;

    float2 wsacc = make_float2(0.f, 0.f);
    float2 asacc = make_float2(0.f, 0.f);
    int t0 = half * 64 + wv * 16;
    size_t bt0 = (size_t)b * 128 + t0;

    float2 xp, yp;
    xp.x = xin[(bt0 + 0) * 40 + rl0];
    xp.y = xin[(bt0 + 1) * 40 + rl0];
    yp.x = yin[(bt0 + 0) * 64 + lane];
    yp.y = yin[(bt0 + 1) * 64 + lane];

#pragma unroll 1
    for (int it = 0; it < 8; ++it) {
        float2 xv = xp, yv = yp;
        float2 bt2 = make_float2(betap[t0 + 2 * it], betap[t0 + 2 * it + 1]);
        if (it < 7) {
            size_t gn = bt0 + 2 * it + 2;
            xp.x = xin[(gn + 0) * 40 + rl0];
            xp.y = xin[(gn + 1) * 40 + rl0];
            yp.x = yin[(gn + 0) * 64 + lane];
            yp.y = yin[(gn + 1) * 64 + lane];
        }
        if (lane >= 40) xv = make_float2(0.f, 0.f);

        // t1 = (K y)_d, t2 = (B y)_d per stream; table quads shared
        float2 t1a = make_float2(0.f, 0.f), t1b = t1a, t2a = t1a, t2b = t1a;
#pragma unroll
        for (int q = 0; q < 32; ++q) {
            float4 kb = KBrow[q];
            float2 y0 = rlane2(yv, 2 * q);
            float2 y1 = rlane2(yv, 2 * q + 1);
            t1a.x = fmaf(kb.x, y0.x, t1a.x); t1a.y = fmaf(kb.x, y0.y, t1a.y);
            t1b.x = fmaf(kb.y, y1.x, t1b.x); t1b.y = fmaf(kb.y, y1.y, t1b.y);
            t2a.x = fmaf(kb.z, y0.x, t2a.x); t2a.y = fmaf(kb.z, y0.y, t2a.y);
            t2b.x = fmaf(kb.w, y1.x, t2b.x); t2b.y = fmaf(kb.w, y1.y, t2b.y);
        }

        float2 A[41];
        A[40].x = fmaf(xv.x, t1a.x + t1b.x, t2a.x + t2b.x);
        A[40].y = fmaf(xv.y, t1a.y + t1b.y, t2a.y + t2b.y);
#pragma unroll
        for (int e = 0; e < 40; ++e) {
            float4 q4 = Qrow[e];
            float2 sxe = rlane2(xv, e);
            A[e].x = fmaf(sxe.x, fmaf(xv.x, q4.x, q4.y), fmaf(xv.x, q4.z, q4.w));
            A[e].y = fmaf(sxe.y, fmaf(xv.y, q4.x, q4.y), fmaf(xv.y, q4.z, q4.w));
        }

        // GE forward elimination (PD Gram, no pivoting), 2 streams interleaved
        float2 rpl = make_float2(0.f, 0.f);
#pragma unroll
        for (int k = 0; k < 40; ++k) {
            float2 piv = rlane2(A[k], k);
            float2 rp;
            rp.x = __builtin_amdgcn_rcpf(piv.x);
            rp.y = __builtin_amdgcn_rcpf(piv.y);
            bool eq = (lane == k);
            rpl.x = eq ? rp.x : rpl.x;
            rpl.y = eq ? rp.y : rpl.y;
            bool gt = (lane > k);
            float2 m;
            m.x = gt ? A[k].x * rp.x : 0.f;
            m.y = gt ? A[k].y * rp.y : 0.f;
#pragma unroll
            for (int jj = k + 1; jj <= 40; ++jj) {
                float2 r = rlane2(A[jj], k);
                A[jj].x = fmaf(-m.x, r.x, A[jj].x);
                A[jj].y = fmaf(-m.y, r.y, A[jj].y);
            }
        }

        // Back substitution (division-free)
        float2 acc = A[40];
        float2 alpha = make_float2(0.f, 0.f);
#pragma unroll
        for (int k = 39; k >= 0; --k) {
            float2 na = rlane2(acc, k);
            float2 rk = rlane2(rpl, k);
            float2 xk = make_float2(na.x * rk.x, na.y * rk.y);
            bool eq = (lane == k);
            alpha.x = eq ? xk.x : alpha.x;
            alpha.y = eq ? xk.y : alpha.y;
            acc.x = fmaf(-xk.x, A[k].x, acc.x);
            acc.y = fmaf(-xk.y, A[k].y, acc.y);
        }

        wsacc.x = fmaf(bt2.x, alpha.x * xv.x, wsacc.x);
        wsacc.y = fmaf(bt2.y, alpha.y * xv.y, wsacc.y);
        asacc.x = fmaf(bt2.x, alpha.x, asacc.x);
        asacc.y = fmaf(bt2.y, alpha.y, asacc.y);
    }

    redW[wv][lane] = wsacc.x + wsacc.y;
    redA[wv][lane] = asacc.x + asacc.y;
    __syncthreads();
    if (tid < 64) {
        wsf[tid] = (redW[0][tid] + redW[1][tid]) + (redW[2][tid] + redW[3][tid]);
    } else if (tid < 128) {
        int d = tid - 64;
        asf[d] = (redA[0][d] + redA[1][d]) + (redA[2][d] + redA[3][d]);
    }
    __syncthreads();
    if (tid < 64) {
        const float* KBf = (const float*)sKB4;
        int u = tid;
        int off = ((u >> 1) << 2) + (u & 1);
        float z = 0.0f;
#pragma unroll
        for (int d = 0; d < 40; ++d) {
            float kv = KBf[d * 132 + off];
            float bv = KBf[d * 132 + off + 2];
            z = fmaf(wsf[d], kv, z);
            z = fmaf(asf[d], bv, z);
        }
        zpart[((size_t)b * 2 + half) * 64 + u] = z;
    }
}

// ---------------------------------------------------------------------------
// Kernel D: deterministic final reduce over the 2 half-blocks per b.
// ---------------------------------------------------------------------------
__global__ void reduce_kernel(const float* __restrict__ zpart, float* __restrict__ out) {
    int idx = blockIdx.x * 256 + threadIdx.x;  // 16384 = 256*64
    int b = idx >> 6, u = idx & 63;
    const float* zp = zpart + (size_t)b * 2 * 64 + u;
    out[idx] = zp[0] + zp[64];
}

// ---------------------------------------------------------------------------
extern "C" void kernel_launch(void* const* d_in, const int* in_sizes, int n_in,
                              void* d_out, int out_size, void* d_ws, size_t ws_size,
                              hipStream_t stream) {
    const float* x  = (const float*)d_in[0];
    const float* W0 = (const float*)d_in[1];
    const float* U0 = (const float*)d_in[2];
    const float* b0 = (const float*)d_in[3];
    const float* W1 = (const float*)d_in[4];
    const float* U1 = (const float*)d_in[5];
    const float* b1 = (const float*)d_in[6];
    const float* Kg = (const float*)d_in[7];
    const float* Bg = (const float*)d_in[8];
    const float* bw = (const float*)d_in[9];
    float* out = (float*)d_out;

    float* y     = (float*)d_ws;                   // 2,097,152 f32
    float4* Qg   = (float4*)(y + 256 * 128 * 64);  // 1600 float4
    float4* KBg  = Qg + 1600;                      // 1280 float4
    float* beta  = (float*)(KBg + 1280);           // 128 f32
    float* zpart = beta + 128;                     // 32,768 f32

    precompute_kernel<<<12, 256, 0, stream>>>(Kg, Bg, bw, Qg, KBg, beta);
    lstm2_kernel<<<256, 512, 0, stream>>>(x, W0, U0, b0, W1, U1, b1, y);
    attn_kernel<<<512, 256, 0, stream>>>(x, y, Qg, KBg, beta, zpart);
    reduce_kernel<<<64, 256, 0, stream>>>(zpart, out);
}

// Round 9
// 346.913 us; speedup vs baseline: 1.9710x; 1.1432x over previous
//
#include <hip/hip_runtime.h>
#include <math.h>

#define DEVI __device__ __forceinline__

DEVI float rlane(float v, int l) {
    return __builtin_bit_cast(float, __builtin_amdgcn_readlane(__builtin_bit_cast(int, v), l));
}
DEVI float sigf(float v) { return 1.0f / (1.0f + __expf(-v)); }
DEVI float tanh_f(float v) {
    v = fminf(fmaxf(v, -15.0f), 15.0f);
    float e = __expf(2.0f * v);
    return (e - 1.0f) / (e + 1.0f);
}

// ---------------------------------------------------------------------------
// Kernel A: fused (b,t)-independent tables.
//   Qg[d*40+e]  = {kk[d][e], kb[e][d], kb[d][e], bb[d][e]}
//   KBg[d*32+q] = {K[d][2q], K[d][2q+1], B[d][2q], B[d][2q+1]}
//   beta[t]     = (|bw_t|+1e-8)/sum
// ---------------------------------------------------------------------------
__global__ void precompute_kernel(const float* __restrict__ Kg, const float* __restrict__ Bg,
                                  const float* __restrict__ betaw,
                                  float4* __restrict__ Qg, float4* __restrict__ KBg,
                                  float* __restrict__ beta) {
    int job = blockIdx.x * 256 + threadIdx.x;
    if (job < 1600) {
        int d = job / 40, e = job - d * 40;
        const float* kd = Kg + d * 64;
        const float* ke = Kg + e * 64;
        const float* bd = Bg + d * 64;
        const float* be = Bg + e * 64;
        float kk = 0, kbT = 0, kbr = 0, bb = 0;
        for (int u = 0; u < 64; ++u) {
            kk  = fmaf(kd[u], ke[u], kk);
            kbT = fmaf(ke[u], bd[u], kbT);
            kbr = fmaf(kd[u], be[u], kbr);
            bb  = fmaf(bd[u], be[u], bb);
        }
        Qg[job] = make_float4(kk, kbT, kbr, bb);
    } else if (job < 2880) {
        int j2 = job - 1600;
        int d = j2 >> 5, q = j2 & 31;
        KBg[j2] = make_float4(Kg[d * 64 + 2 * q], Kg[d * 64 + 2 * q + 1],
                              Bg[d * 64 + 2 * q], Bg[d * 64 + 2 * q + 1]);
    }
    if (blockIdx.x == 0) {
        int tid = threadIdx.x;
        __shared__ float red[256];
        float av = (tid < 128) ? (fabsf(betaw[tid]) + 1e-8f) : 0.0f;
        red[tid] = av;
        __syncthreads();
        for (int s = 128; s > 0; s >>= 1) {
            if (tid < s) red[tid] += red[tid + s];
            __syncthreads();
        }
        float tot = red[0];
        if (tid < 128) beta[tid] = av / tot;
    }
}

// ---------------------------------------------------------------------------
// Kernel B: BOTH LSTM layers in one kernel, software-pipelined over t
// (proven R8). Group A (waves 0-3) = layer 1 step s; group B = layer 2 step
// s-1. 129 steps, 2 barriers each.
// ---------------------------------------------------------------------------
__global__ __launch_bounds__(512)
void lstm2_kernel(const float* __restrict__ x,
                  const float* __restrict__ W0, const float* __restrict__ U0,
                  const float* __restrict__ b0,
                  const float* __restrict__ W1, const float* __restrict__ U1,
                  const float* __restrict__ b1,
                  float* __restrict__ y) {
    int b = blockIdx.x;
    int tid = threadIdx.x;
    int j = tid & 255;
    int u = tid & 63;
    int lane = tid & 63;
    int grp = __builtin_amdgcn_readfirstlane(tid) >> 8;

    float wcol[64];
    float ucol[64];
    float bj;
    if (grp == 0) {
#pragma unroll
        for (int d = 0; d < 40; ++d) wcol[d] = W0[d * 256 + j];
#pragma unroll
        for (int k = 0; k < 64; ++k) ucol[k] = U0[k * 256 + j];
        bj = b0[j];
    } else {
#pragma unroll
        for (int k = 0; k < 64; ++k) wcol[k] = W1[k * 256 + j];
#pragma unroll
        for (int k = 0; k < 64; ++k) ucol[k] = U1[k * 256 + j];
        bj = b1[j];
    }

    __shared__ float x_lds[128 * 40];
    __shared__ float a_lds[512];
    __shared__ float h1buf[64];
    __shared__ float h2buf[64];
    const float4* xg = (const float4*)(x + (size_t)b * 128 * 40);
    float4* xl = (float4*)x_lds;
    for (int i = tid; i < 128 * 40 / 4; i += 512) xl[i] = xg[i];
    if (tid < 64) { h1buf[tid] = 0.0f; h2buf[tid] = 0.0f; }
    float c1 = 0.0f, c2 = 0.0f;
    __syncthreads();

    int li = (lane < 40) ? lane : 0;
#pragma unroll 1
    for (int s = 0; s <= 128; ++s) {
        float a0 = bj, a1 = 0.0f, a2 = 0.0f, a3 = 0.0f;
        if (grp == 0) {
            if (s < 128) {
                float xv = x_lds[s * 40 + li];
                float hv = h1buf[lane];
#pragma unroll
                for (int d = 0; d < 40; d += 4) {
                    a0 = fmaf(rlane(xv, d), wcol[d], a0);
                    a1 = fmaf(rlane(xv, d + 1), wcol[d + 1], a1);
                    a2 = fmaf(rlane(xv, d + 2), wcol[d + 2], a2);
                    a3 = fmaf(rlane(xv, d + 3), wcol[d + 3], a3);
                }
#pragma unroll
                for (int k = 0; k < 64; k += 4) {
                    a0 = fmaf(rlane(hv, k), ucol[k], a0);
                    a1 = fmaf(rlane(hv, k + 1), ucol[k + 1], a1);
                    a2 = fmaf(rlane(hv, k + 2), ucol[k + 2], a2);
                    a3 = fmaf(rlane(hv, k + 3), ucol[k + 3], a3);
                }
            }
        } else {
            if (s >= 1) {
                float h1x = h1buf[lane];
                float h2v = h2buf[lane];
#pragma unroll
                for (int k = 0; k < 64; k += 4) {
                    a0 = fmaf(rlane(h1x, k), wcol[k], a0);
                    a1 = fmaf(rlane(h1x, k + 1), wcol[k + 1], a1);
                    a2 = fmaf(rlane(h1x, k + 2), wcol[k + 2], a2);
                    a3 = fmaf(rlane(h1x, k + 3), wcol[k + 3], a3);
                }
#pragma unroll
                for (int k = 0; k < 64; k += 4) {
                    a0 = fmaf(rlane(h2v, k), ucol[k], a0);
                    a1 = fmaf(rlane(h2v, k + 1), ucol[k + 1], a1);
                    a2 = fmaf(rlane(h2v, k + 2), ucol[k + 2], a2);
                    a3 = fmaf(rlane(h2v, k + 3), ucol[k + 3], a3);
                }
            }
        }
        float z = (a0 + a1) + (a2 + a3);
        int g = (tid >> 6) & 3;
        float a = (g == 2) ? tanh_f(z) : sigf(z);
        a_lds[tid] = a;
        __syncthreads();
        if (grp == 0) {
            if (tid < 64 && s < 128) {
                float iv = a_lds[u], fv = a_lds[u + 64];
                float gv = a_lds[u + 128], ov = a_lds[u + 192];
                c1 = fmaf(fv, c1, iv * gv);
                h1buf[u] = ov * tanh_f(c1);
            }
        } else {
            if (tid < 320 && s >= 1) {
                float iv = a_lds[256 + u], fv = a_lds[320 + u];
                float gv = a_lds[384 + u], ov = a_lds[448 + u];
                c2 = fmaf(fv, c2, iv * gv);
                float h2 = ov * tanh_f(c2);
                h2buf[u] = h2;
                y[((size_t)b * 128 + (s - 1)) * 64 + u] = h2;
            }
        }
        __syncthreads();
    }
}

// ---------------------------------------------------------------------------
// Kernel C: attention. NS=2 register-GE (proven), now with wave-uniform
// SCALAR loads for x/y/beta (s_load + SGPR fma operands: no yv VGPRs, no
// KY/build readlanes), rpl eliminated (rcp recomputed in backsub), and
// 1024 blocks x 256 thr (8 t per wave) so 3 waves/SIMD is reachable if
// VGPR <= 170. UNCAPPED: occupancy attributes cause scratch spill (R2/R3/R7).
// ---------------------------------------------------------------------------
__launch_bounds__(256)
__global__ void attn_kernel(const float* __restrict__ xin, const float* __restrict__ yin,
                            const float4* __restrict__ Qg, const float4* __restrict__ KBg,
                            const float* __restrict__ betap, float* __restrict__ zpart) {
    __shared__ float4 sQ4[40 * 41];   // 26.2 KB
    __shared__ float4 sKB4[40 * 33];  // 21.1 KB
    __shared__ float redW[4][64];
    __shared__ float redA[4][64];
    __shared__ float wsf[64];
    __shared__ float asf[64];
    int tid = threadIdx.x;
    for (int i = tid; i < 1600; i += 256) {
        int d = i / 40, e = i - d * 40;
        sQ4[d * 41 + e] = Qg[i];
    }
    for (int i = tid; i < 1280; i += 256) {
        int d = i >> 5, q = i & 31;
        sKB4[d * 33 + q] = KBg[i];
    }
    __syncthreads();

    int b = blockIdx.x >> 2;          // 4 blocks per batch row
    int qq = blockIdx.x & 3;
    int wv = tid >> 6;
    int lane = tid & 63;
    int rl0 = (lane < 40) ? lane : 39;
    const float4* Qrow = sQ4 + rl0 * 41;
    const float4* KBrow = sKB4 + rl0 * 33;

    float2 wsacc = make_float2(0.f, 0.f);
    float2 asacc = make_float2(0.f, 0.f);
    int su = __builtin_amdgcn_readfirstlane(wv);      // wave-uniform wave id
    int t0u = qq * 32 + su * 8;                       // uniform t base
    size_t bt0u = (size_t)b * 128 + t0u;

#pragma unroll 1
    for (int it = 0; it < 4; ++it) {
        // Wave-uniform row pointers -> scalar (SGPR) operand loads
        const float* yr0 = yin + (bt0u + 2 * it) * 64;
        const float* yr1 = yr0 + 64;
        const float* xr0 = xin + (bt0u + 2 * it) * 40;
        const float* xr1 = xr0 + 40;
        float btx = betap[t0u + 2 * it];
        float bty = betap[t0u + 2 * it + 1];

        // Per-lane x values (lane = row d)
        float2 xv;
        xv.x = xr0[rl0];
        xv.y = xr1[rl0];
        if (lane >= 40) { xv.x = 0.f; xv.y = 0.f; }

        // t1 = (K y)_d, t2 = (B y)_d per stream; y via scalar loads
        float2 t1a = make_float2(0.f, 0.f), t1b = t1a, t2a = t1a, t2b = t1a;
#pragma unroll
        for (int q = 0; q < 32; ++q) {
            float4 kb = KBrow[q];
            float s0x = yr0[2 * q], s1x = yr0[2 * q + 1];
            float s0y = yr1[2 * q], s1y = yr1[2 * q + 1];
            t1a.x = fmaf(kb.x, s0x, t1a.x); t1a.y = fmaf(kb.x, s0y, t1a.y);
            t1b.x = fmaf(kb.y, s1x, t1b.x); t1b.y = fmaf(kb.y, s1y, t1b.y);
            t2a.x = fmaf(kb.z, s0x, t2a.x); t2a.y = fmaf(kb.z, s0y, t2a.y);
            t2b.x = fmaf(kb.w, s1x, t2b.x); t2b.y = fmaf(kb.w, s1y, t2b.y);
        }

        // Augmented rows; x broadcasts via scalar loads
        float2 A[41];
        A[40].x = fmaf(xv.x, t1a.x + t1b.x, t2a.x + t2b.x);
        A[40].y = fmaf(xv.y, t1a.y + t1b.y, t2a.y + t2b.y);
#pragma unroll
        for (int e = 0; e < 40; ++e) {
            float4 q4 = Qrow[e];
            float sxx = xr0[e];
            float sxy = xr1[e];
            A[e].x = fmaf(sxx, fmaf(xv.x, q4.x, q4.y), fmaf(xv.x, q4.z, q4.w));
            A[e].y = fmaf(sxy, fmaf(xv.y, q4.x, q4.y), fmaf(xv.y, q4.z, q4.w));
        }

        // GE forward elimination (PD Gram, no pivoting), 2 streams interleaved
#pragma unroll
        for (int k = 0; k < 40; ++k) {
            float rpx = __builtin_amdgcn_rcpf(rlane(A[k].x, k));
            float rpy = __builtin_amdgcn_rcpf(rlane(A[k].y, k));
            bool gt = (lane > k);
            float mx = gt ? A[k].x * rpx : 0.f;
            float my = gt ? A[k].y * rpy : 0.f;
#pragma unroll
            for (int jj = k + 1; jj <= 40; ++jj) {
                A[jj].x = fmaf(-mx, rlane(A[jj].x, k), A[jj].x);
                A[jj].y = fmaf(-my, rlane(A[jj].y, k), A[jj].y);
            }
        }

        // Back substitution; pivot reciprocal recomputed (no rpl array)
        float2 acc = A[40];
        float2 alpha = make_float2(0.f, 0.f);
#pragma unroll
        for (int k = 39; k >= 0; --k) {
            float xk = rlane(acc.x, k) * __builtin_amdgcn_rcpf(rlane(A[k].x, k));
            float yk = rlane(acc.y, k) * __builtin_amdgcn_rcpf(rlane(A[k].y, k));
            bool eq = (lane == k);
            alpha.x = eq ? xk : alpha.x;
            alpha.y = eq ? yk : alpha.y;
            acc.x = fmaf(-xk, A[k].x, acc.x);
            acc.y = fmaf(-yk, A[k].y, acc.y);
        }

        wsacc.x = fmaf(btx, alpha.x * xv.x, wsacc.x);
        wsacc.y = fmaf(bty, alpha.y * xv.y, wsacc.y);
        asacc.x = fmaf(btx, alpha.x, asacc.x);
        asacc.y = fmaf(bty, alpha.y, asacc.y);
    }

    redW[wv][lane] = wsacc.x + wsacc.y;
    redA[wv][lane] = asacc.x + asacc.y;
    __syncthreads();
    if (tid < 64) {
        wsf[tid] = (redW[0][tid] + redW[1][tid]) + (redW[2][tid] + redW[3][tid]);
    } else if (tid < 128) {
        int d = tid - 64;
        asf[d] = (redA[0][d] + redA[1][d]) + (redA[2][d] + redA[3][d]);
    }
    __syncthreads();
    if (tid < 64) {
        const float* KBf = (const float*)sKB4;
        int u = tid;
        int off = ((u >> 1) << 2) + (u & 1);
        float z = 0.0f;
#pragma unroll
        for (int d = 0; d < 40; ++d) {
            float kv = KBf[d * 132 + off];
            float bv = KBf[d * 132 + off + 2];
            z = fmaf(wsf[d], kv, z);
            z = fmaf(asf[d], bv, z);
        }
        zpart[((size_t)b * 4 + qq) * 64 + u] = z;
    }
}

// ---------------------------------------------------------------------------
// Kernel D: deterministic final reduce over the 4 quarter-blocks per b.
// ---------------------------------------------------------------------------
__global__ void reduce_kernel(const float* __restrict__ zpart, float* __restrict__ out) {
    int idx = blockIdx.x * 256 + threadIdx.x;  // 16384 = 256*64
    int b = idx >> 6, u = idx & 63;
    const float* zp = zpart + (size_t)b * 4 * 64 + u;
    out[idx] = (zp[0] + zp[64]) + (zp[128] + zp[192]);
}

// ---------------------------------------------------------------------------
extern "C" void kernel_launch(void* const* d_in, const int* in_sizes, int n_in,
                              void* d_out, int out_size, void* d_ws, size_t ws_size,
                              hipStream_t stream) {
    const float* x  = (const float*)d_in[0];
    const float* W0 = (const float*)d_in[1];
    const float* U0 = (const float*)d_in[2];
    const float* b0 = (const float*)d_in[3];
    const float* W1 = (const float*)d_in[4];
    const float* U1 = (const float*)d_in[5];
    const float* b1 = (const float*)d_in[6];
    const float* Kg = (const float*)d_in[7];
    const float* Bg = (const float*)d_in[8];
    const float* bw = (const float*)d_in[9];
    float* out = (float*)d_out;

    float* y     = (float*)d_ws;                   // 2,097,152 f32
    float4* Qg   = (float4*)(y + 256 * 128 * 64);  // 1600 float4
    float4* KBg  = Qg + 1600;                      // 1280 float4
    float* beta  = (float*)(KBg + 1280);           // 128 f32
    float* zpart = beta + 128;                     // 65,536 f32

    precompute_kernel<<<12, 256, 0, stream>>>(Kg, Bg, bw, Qg, KBg, beta);
    lstm2_kernel<<<256, 512, 0, stream>>>(x, W0, U0, b0, W1, U1, b1, y);
    attn_kernel<<<1024, 256, 0, stream>>>(x, y, Qg, KBg, beta, zpart);
    reduce_kernel<<<64, 256, 0, stream>>>(zpart, out);
}